// Round 5
// baseline (102.311 us; speedup 1.0000x reference)
//
#include <hip/hip_runtime.h>

#define H 384
#define W 384
#define C 19
#define NB 4
#define HP 382               // H - K + 1
#define HW (H * W)
#define CHW (C * HW)
#define TOTAL_TERMS 47279376.0f   // NB * 81 * HP*HP

// number of kernel-offsets a in [0,2] with 0 <= a+d <= 2 and 0 <= p-a <= HP-1
__device__ __forceinline__ int multv(int p, int d) {
    int lo = max(max(0, -d), p - (HP - 1));
    int hi = min(min(2, 2 - d), p);
    return max(0, hi - lo + 1);
}

__device__ __forceinline__ float bce_fast(float x, float y) {
    // max(x,0) - x*y + log1p(exp(-|x|)), fast-math variant
    float t = __expf(-fabsf(x));
    return fmaxf(x, 0.0f) - x * y + __logf(1.0f + t);
}

// 4 waves per block; the block owns 64 pixel-groups (4 px each, lane = group).
//   wid&1  : offset-row parity. par0: (0,0),(0,1),(0,2),(2,-2..2) -> rows {0,2}
//            par1: (1,-2..2)                                      -> row 1
//   wid>>1 : channel half, COMPILE-TIME bounds: [0,10) or [10,19)
// Upper channel-half waves write partial dots to LDS (transposed, conflict-
// free); lower waves add them, then do the BCE epilogue. All branches are
// wave-uniform -> zero divergence. Grid: 147456 groups / 64 = 2304 blocks.
__global__ __launch_bounds__(256, 8) void affinity_partial(
        const float* __restrict__ logits,
        const int* __restrict__ labels,
        float* __restrict__ partial) {
    const int wid  = threadIdx.x >> 6;
    const int lane = threadIdx.x & 63;
    const int par  = wid & 1;
    const int g    = blockIdx.x * 64 + lane;
    const int px0  = (g % 96) * 4;
    const int rs   = g / 96;
    const int py   = rs % H;
    const int n    = rs / H;

    // staging window cols x0c..x0c+11 via aligned float4 at +0, +d1, +d2.
    // invariant (weight>0 terms): arr[j] == column px0 + j - 4.
    const int x0c = max(0, px0 - 4);
    const int d1  = px0 - x0c;                 // 0 or 4
    const int d2  = min(W - 4, px0 + 4) - x0c; // 4 or 8
    const int ro1 = (min(py + 1, H - 1) - py) * W;
    const int ro2 = (min(py + 2, H - 1) - py) * W;

    const float* p0 = logits + (size_t)n * CHW + (size_t)py * W + x0c;

    __shared__ float comb[2][32][64];   // [parity][acc][lane] — transposed

    float acc[32];
#pragma unroll
    for (int k = 0; k < 32; ++k) acc[k] = 0.0f;

    if (par == 0) {
        // offsets (0,0),(0,1),(0,2) -> acc[i*8+0..2]; (2,dxi-2) -> acc[i*8+3+dxi]
#define CLOOP0(CB, CE)                                                  \
        _Pragma("unroll")                                               \
        for (int c = (CB); c < (CE); ++c) {                             \
            const float* pr = p0 + (size_t)c * HW;                      \
            float a[12], e[12];                                         \
            *(float4*)&a[0] = *(const float4*)(pr);                     \
            *(float4*)&a[4] = *(const float4*)(pr + d1);                \
            *(float4*)&a[8] = *(const float4*)(pr + d2);                \
            *(float4*)&e[0] = *(const float4*)(pr + ro2);               \
            *(float4*)&e[4] = *(const float4*)(pr + ro2 + d1);          \
            *(float4*)&e[8] = *(const float4*)(pr + ro2 + d2);          \
            _Pragma("unroll")                                           \
            for (int i = 0; i < 4; ++i) {                               \
                const float s = a[4 + i];                               \
                acc[i * 8 + 0] += s * s;                                \
                acc[i * 8 + 1] += s * a[5 + i];                         \
                acc[i * 8 + 2] += s * a[6 + i];                         \
                _Pragma("unroll")                                       \
                for (int dxi = 0; dxi < 5; ++dxi)                       \
                    acc[i * 8 + 3 + dxi] += s * e[2 + i + dxi];         \
            }                                                           \
        }
        if ((wid >> 1) == 0) { CLOOP0(0, 10) } else { CLOOP0(10, 19) }
    } else {
        // offsets (1,dxi-2) -> acc[i*5+dxi]
#define CLOOP1(CB, CE)                                                  \
        _Pragma("unroll")                                               \
        for (int c = (CB); c < (CE); ++c) {                             \
            const float* pr = p0 + (size_t)c * HW;                      \
            float sa[4], b[12];                                         \
            *(float4*)&sa[0] = *(const float4*)(pr + d1);               \
            *(float4*)&b[0]  = *(const float4*)(pr + ro1);              \
            *(float4*)&b[4]  = *(const float4*)(pr + ro1 + d1);         \
            *(float4*)&b[8]  = *(const float4*)(pr + ro1 + d2);         \
            _Pragma("unroll")                                           \
            for (int i = 0; i < 4; ++i) {                               \
                const float s = sa[i];                                  \
                _Pragma("unroll")                                       \
                for (int dxi = 0; dxi < 5; ++dxi)                       \
                    acc[i * 5 + dxi] += s * b[2 + i + dxi];             \
            }                                                           \
        }
        if ((wid >> 1) == 0) { CLOOP1(0, 10) } else { CLOOP1(10, 19) }
    }

    // upper channel-half waves publish partial dots (conflict-free: lane-major)
    if (wid == 2) {
#pragma unroll
        for (int k = 0; k < 32; ++k) comb[0][k][lane] = acc[k];
    } else if (wid == 3) {
#pragma unroll
        for (int k = 0; k < 20; ++k) comb[1][k][lane] = acc[k];
    }
    __syncthreads();

    float total = 0.0f;
    const int* lb0 = labels + (size_t)n * HW + (size_t)py * W + x0c;

    if (wid == 0) {
#pragma unroll
        for (int k = 0; k < 32; ++k) acc[k] += comb[0][k][lane];

        int la[12], ler[12];
        *(int4*)&la[0]  = *(const int4*)(lb0);
        *(int4*)&la[4]  = *(const int4*)(lb0 + d1);
        *(int4*)&la[8]  = *(const int4*)(lb0 + d2);
        *(int4*)&ler[0] = *(const int4*)(lb0 + ro2);
        *(int4*)&ler[4] = *(const int4*)(lb0 + ro2 + d1);
        *(int4*)&ler[8] = *(const int4*)(lb0 + ro2 + d2);

        const int wy0 = multv(py, 0);
        const int wy2 = multv(py, 2);
#pragma unroll
        for (int i = 0; i < 4; ++i) {
            const int px = px0 + i;
            int wx[5];
#pragma unroll
            for (int dxi = 0; dxi < 5; ++dxi) wx[dxi] = multv(px, dxi - 2);
            const int ls = la[4 + i];
            total += (float)(wy0 * wx[2]) * bce_fast(acc[i * 8 + 0], 1.0f);
            total += 2.0f * (float)(wy0 * wx[3]) *
                     bce_fast(acc[i * 8 + 1], (ls == la[5 + i]) ? 1.0f : 0.0f);
            total += 2.0f * (float)(wy0 * wx[4]) *
                     bce_fast(acc[i * 8 + 2], (ls == la[6 + i]) ? 1.0f : 0.0f);
#pragma unroll
            for (int dxi = 0; dxi < 5; ++dxi)
                total += 2.0f * (float)(wy2 * wx[dxi]) *
                         bce_fast(acc[i * 8 + 3 + dxi],
                                  (ls == ler[2 + i + dxi]) ? 1.0f : 0.0f);
        }
    } else if (wid == 1) {
#pragma unroll
        for (int k = 0; k < 20; ++k) acc[k] += comb[1][k][lane];

        int la4[4], lbr[12];
        *(int4*)&la4[0] = *(const int4*)(lb0 + d1);
        *(int4*)&lbr[0] = *(const int4*)(lb0 + ro1);
        *(int4*)&lbr[4] = *(const int4*)(lb0 + ro1 + d1);
        *(int4*)&lbr[8] = *(const int4*)(lb0 + ro1 + d2);

        const int wy1 = multv(py, 1);
#pragma unroll
        for (int i = 0; i < 4; ++i) {
            const int px = px0 + i;
            int wx[5];
#pragma unroll
            for (int dxi = 0; dxi < 5; ++dxi) wx[dxi] = multv(px, dxi - 2);
            const int ls = la4[i];
#pragma unroll
            for (int dxi = 0; dxi < 5; ++dxi)
                total += 2.0f * (float)(wy1 * wx[dxi]) *
                         bce_fast(acc[i * 5 + dxi],
                                  (ls == lbr[2 + i + dxi]) ? 1.0f : 0.0f);
        }
    }

    // block reduction: wave shuffle then LDS across the 4 waves
#pragma unroll
    for (int off = 32; off > 0; off >>= 1) total += __shfl_down(total, off, 64);
    __shared__ float sm[4];
    if (lane == 0) sm[wid] = total;
    __syncthreads();
    if (threadIdx.x == 0)
        partial[blockIdx.x] = sm[0] + sm[1] + sm[2] + sm[3];
}

__global__ __launch_bounds__(256) void reduce_final(
        const float* __restrict__ partial, int n, float* __restrict__ out) {
    float s = 0.0f;
    for (int i = threadIdx.x; i < n; i += 256) s += partial[i];
#pragma unroll
    for (int off = 32; off > 0; off >>= 1) s += __shfl_down(s, off, 64);
    __shared__ float sm[4];
    const int lane = threadIdx.x & 63, wid = threadIdx.x >> 6;
    if (lane == 0) sm[wid] = s;
    __syncthreads();
    if (threadIdx.x == 0)
        out[0] = (sm[0] + sm[1] + sm[2] + sm[3]) / TOTAL_TERMS;
}

extern "C" void kernel_launch(void* const* d_in, const int* in_sizes, int n_in,
                              void* d_out, int out_size, void* d_ws, size_t ws_size,
                              hipStream_t stream) {
    const float* logits = (const float*)d_in[0];
    const int*   labels = (const int*)d_in[1];
    float* out     = (float*)d_out;
    float* partial = (float*)d_ws;   // 2304 floats

    const int ngroups = NB * H * 96;          // 147456 pixel groups
    const int nblocks = ngroups / 64;         // 2304

    affinity_partial<<<nblocks, 256, 0, stream>>>(logits, labels, partial);
    reduce_final<<<1, 256, 0, stream>>>(partial, nblocks, out);
}

// Round 6
// 48.329 us; speedup vs baseline: 2.1170x; 2.1170x over previous
//
#include <hip/hip_runtime.h>

#define H 384
#define W 384
#define C 19
#define NB 4
#define HP 382               // H - K + 1
#define HW (H * W)
#define CHW (C * HW)
#define TOTAL_TERMS 47279376.0f   // NB * 81 * HP*HP

#define TROWS 16
#define TCOLS 64
#define LROWS 18                      // TROWS + 2 halo rows
#define LSTRIDE 72                    // floats per LDS row (16B-aligned stride)
#define LBUF (LROWS * LSTRIDE)        // 1296 floats per buffer
#define NSLOTS (LROWS * (LSTRIDE / 4))  // 324 float4 slots per buffer

// number of kernel-offsets a in [0,2] with 0 <= a+d <= 2 and 0 <= p-a <= HP-1
__device__ __forceinline__ int multv(int p, int d) {
    int lo = max(max(0, -d), p - (HP - 1));
    int hi = min(min(2, 2 - d), p);
    return max(0, hi - lo + 1);
}

__device__ __forceinline__ float bce_fast(float x, float y) {
    // max(x,0) - x*y + log1p(exp(-|x|)), fast-math variant
    float t = __expf(-fabsf(x));
    return fmaxf(x, 0.0f) - x * y + __logf(1.0f + t);
}

// One block = 16x64-pixel tile, 256 threads, 4 px/thread (ty = t>>4, tx = t&15).
// Per channel: stage (18 x 72)-float halo tile into LDS (double-buffered,
// loads issued before compute, ds_write after), then each thread reads its
// 3x12-float window via 9x ds_read_b128 and accumulates 13 offset-dots.
// Grid: 4 * (384/16) * (384/64) = 576 blocks.
__global__ __launch_bounds__(256) void affinity_partial(
        const float* __restrict__ logits,
        const int* __restrict__ labels,
        float* __restrict__ partial) {
    const int t  = threadIdx.x;
    const int tx = t & 15;
    const int ty = t >> 4;

    const int b   = blockIdx.x;          // 0..575
    const int n   = b / 144;
    const int rem = b % 144;
    const int ty0 = (rem / 6) * TROWS;
    const int tx0 = (rem % 6) * TCOLS;

    // staging slot(s): slot s covers LDS row s/18, float4 col s%18.
    // Global row/col clamped; clamped (duplicated) cells only feed weight-0
    // terms (multv == 0 outside the image), so garbage there is harmless.
    const int r1 = t / 18, j1 = t % 18;
    const int goff1 = min(ty0 + r1, H - 1) * W + min(max(tx0 - 4 + 4 * j1, 0), W - 4);
    const int loff1 = r1 * LSTRIDE + 4 * j1;
    const bool has2 = (t < NSLOTS - 256);    // t < 68
    const int s2 = t + 256;
    const int r2 = s2 / 18, j2 = s2 % 18;
    const int goff2 = min(ty0 + r2, H - 1) * W + min(max(tx0 - 4 + 4 * j2, 0), W - 4);
    const int loff2 = r2 * LSTRIDE + 4 * j2;

    __shared__ __align__(16) float lds[2 * LBUF];   // 10368 B

    const float* srcb = logits + (size_t)n * CHW;

    // prologue: stage channel 0 into buffer 0
    {
        float4 v1 = *(const float4*)(srcb + goff1);
        *(float4*)&lds[loff1] = v1;
        if (has2) {
            float4 v2 = *(const float4*)(srcb + goff2);
            *(float4*)&lds[loff2] = v2;
        }
    }
    __syncthreads();

    const int rbase = ty * LSTRIDE + 4 * tx;   // window: LDS cols 4tx..4tx+11
                                               // == global cols px0-4..px0+7

    float acc[4][13];
#pragma unroll
    for (int i = 0; i < 4; ++i)
#pragma unroll
        for (int o = 0; o < 13; ++o) acc[i][o] = 0.0f;

#pragma unroll
    for (int c = 0; c < C; ++c) {
        const int sel  = (c & 1) * LBUF;
        const int nsel = LBUF - sel;

        // issue next channel's global loads early (hide HBM/L2 latency under
        // this channel's LDS compute); ds_write them after the compute.
        float4 v1, v2;
        if (c + 1 < C) {
            const float* nsrc = srcb + (size_t)(c + 1) * HW;
            v1 = *(const float4*)(nsrc + goff1);
            if (has2) v2 = *(const float4*)(nsrc + goff2);
        }

        float a[12], bb[12], e[12];
        *(float4*)&a[0]  = *(const float4*)&lds[sel + rbase];
        *(float4*)&a[4]  = *(const float4*)&lds[sel + rbase + 4];
        *(float4*)&a[8]  = *(const float4*)&lds[sel + rbase + 8];
        *(float4*)&bb[0] = *(const float4*)&lds[sel + rbase + LSTRIDE];
        *(float4*)&bb[4] = *(const float4*)&lds[sel + rbase + LSTRIDE + 4];
        *(float4*)&bb[8] = *(const float4*)&lds[sel + rbase + LSTRIDE + 8];
        *(float4*)&e[0]  = *(const float4*)&lds[sel + rbase + 2 * LSTRIDE];
        *(float4*)&e[4]  = *(const float4*)&lds[sel + rbase + 2 * LSTRIDE + 4];
        *(float4*)&e[8]  = *(const float4*)&lds[sel + rbase + 2 * LSTRIDE + 8];

#pragma unroll
        for (int i = 0; i < 4; ++i) {
            const float s = a[4 + i];              // col px0+i
            acc[i][0] += s * s;                    // (0,0)
            acc[i][1] += s * a[5 + i];             // (0,1)
            acc[i][2] += s * a[6 + i];             // (0,2)
#pragma unroll
            for (int dxi = 0; dxi < 5; ++dxi) {
                acc[i][3 + dxi] += s * bb[2 + i + dxi];   // (1, dxi-2)
                acc[i][8 + dxi] += s * e[2 + i + dxi];    // (2, dxi-2)
            }
        }

        if (c + 1 < C) {
            // safe: buffer nsel was last READ in iteration c-1, and every wave
            // passed the end-of-(c-1) barrier already.
            *(float4*)&lds[nsel + loff1] = v1;
            if (has2) *(float4*)&lds[nsel + loff2] = v2;
        }
        __syncthreads();
    }

    // ---- epilogue: labels + weighted BCE (labels straight from global) ----
    const int py  = ty0 + ty;
    const int px0 = tx0 + 4 * tx;
    const int x0c = max(0, px0 - 4);
    const int d1  = px0 - x0c;                 // 0 or 4
    const int d2  = min(W - 4, px0 + 4) - x0c; // 4 or 8
    const int ro1 = (min(py + 1, H - 1) - py) * W;
    const int ro2 = (min(py + 2, H - 1) - py) * W;
    const int* lb0 = labels + (size_t)n * HW + (size_t)py * W + x0c;

    int la[12], lbr[12], ler[12];
    *(int4*)&la[0]  = *(const int4*)(lb0);
    *(int4*)&la[4]  = *(const int4*)(lb0 + d1);
    *(int4*)&la[8]  = *(const int4*)(lb0 + d2);
    *(int4*)&lbr[0] = *(const int4*)(lb0 + ro1);
    *(int4*)&lbr[4] = *(const int4*)(lb0 + ro1 + d1);
    *(int4*)&lbr[8] = *(const int4*)(lb0 + ro1 + d2);
    *(int4*)&ler[0] = *(const int4*)(lb0 + ro2);
    *(int4*)&ler[4] = *(const int4*)(lb0 + ro2 + d1);
    *(int4*)&ler[8] = *(const int4*)(lb0 + ro2 + d2);

    const int wy0 = multv(py, 0);
    const int wy1 = multv(py, 1);
    const int wy2 = multv(py, 2);

    float total = 0.0f;
#pragma unroll
    for (int i = 0; i < 4; ++i) {
        const int px = px0 + i;
        int wx[5];
#pragma unroll
        for (int dxi = 0; dxi < 5; ++dxi) wx[dxi] = multv(px, dxi - 2);
        const int ls = la[4 + i];

        total += (float)(wy0 * wx[2]) * bce_fast(acc[i][0], 1.0f);
        total += 2.0f * (float)(wy0 * wx[3]) *
                 bce_fast(acc[i][1], (ls == la[5 + i]) ? 1.0f : 0.0f);
        total += 2.0f * (float)(wy0 * wx[4]) *
                 bce_fast(acc[i][2], (ls == la[6 + i]) ? 1.0f : 0.0f);
#pragma unroll
        for (int dxi = 0; dxi < 5; ++dxi) {
            total += 2.0f * (float)(wy1 * wx[dxi]) *
                     bce_fast(acc[i][3 + dxi], (ls == lbr[2 + i + dxi]) ? 1.0f : 0.0f);
            total += 2.0f * (float)(wy2 * wx[dxi]) *
                     bce_fast(acc[i][8 + dxi], (ls == ler[2 + i + dxi]) ? 1.0f : 0.0f);
        }
    }

    // block reduction: wave shuffle then LDS across the 4 waves
#pragma unroll
    for (int off = 32; off > 0; off >>= 1) total += __shfl_down(total, off, 64);
    __shared__ float sm[4];
    const int lane = t & 63, wid = t >> 6;
    if (lane == 0) sm[wid] = total;
    __syncthreads();
    if (t == 0)
        partial[blockIdx.x] = sm[0] + sm[1] + sm[2] + sm[3];
}

__global__ __launch_bounds__(256) void reduce_final(
        const float* __restrict__ partial, int n, float* __restrict__ out) {
    float s = 0.0f;
    for (int i = threadIdx.x; i < n; i += 256) s += partial[i];
#pragma unroll
    for (int off = 32; off > 0; off >>= 1) s += __shfl_down(s, off, 64);
    __shared__ float sm[4];
    const int lane = threadIdx.x & 63, wid = threadIdx.x >> 6;
    if (lane == 0) sm[wid] = s;
    __syncthreads();
    if (threadIdx.x == 0)
        out[0] = (sm[0] + sm[1] + sm[2] + sm[3]) / TOTAL_TERMS;
}

extern "C" void kernel_launch(void* const* d_in, const int* in_sizes, int n_in,
                              void* d_out, int out_size, void* d_ws, size_t ws_size,
                              hipStream_t stream) {
    const float* logits = (const float*)d_in[0];
    const int*   labels = (const int*)d_in[1];
    float* out     = (float*)d_out;
    float* partial = (float*)d_ws;   // 576 floats

    const int nblocks = NB * (H / TROWS) * (W / TCOLS);   // 576

    affinity_partial<<<nblocks, 256, 0, stream>>>(logits, labels, partial);
    reduce_final<<<1, 256, 0, stream>>>(partial, nblocks, out);
}